// Round 4
// baseline (237.336 us; speedup 1.0000x reference)
//
#include <hip/hip_runtime.h>
#include <hip/hip_bf16.h>
#include <hip/hip_cooperative_groups.h>

namespace cg = cooperative_groups;

// B=128, V=1024, D=512. ONE cooperative kernel, 512 blocks x 256 thr, 2 grid.sync()s:
//  Phase A: blocks [0,176)  three bf16 MFMA GEMMs (BK=64, LDS dbuf, 1 barrier/iter):
//             fpT=(feat@Wf^T)^T (512x128 f32), ppbT=Wp@proto^T+b1 (512x1024 bf16),
//             dotraw=feat@proto^T (128x1024 f32)
//           blocks [176,192) zipf ranks->zw; [192,480) row inv-norms; [480,512) idle
//  Phase B: blocks [0,256): w[b,v] = (zw/sum zw)*(1+sim)*sigmoid(hs+b2), full K,
//           b-tile 2 (64 bg x 4 v-quarters); writes wbuf
//  Phase C: blocks [0,128): softmax over v per b -> out
// __launch_bounds__(256,2) -> VGPR<=256 -> >=2 blocks/CU resident -> grid 512 valid
// for cooperative launch (2 blk/CU * 37KB LDS = 74KB <= 160KB).

typedef __attribute__((ext_vector_type(8))) short bhalf8;
typedef __attribute__((ext_vector_type(4))) float f32x4;

static __device__ __forceinline__ unsigned short f2bf(float x) {
    union { __hip_bfloat16 h; unsigned short u; } cv;
    cv.h = __float2bfloat16(x);
    return cv.u;
}

static __device__ __forceinline__ float bf2f(unsigned short u) {
    return __uint_as_float(((unsigned int)u) << 16);
}

static __device__ __forceinline__ int4 pack_bf16_8(float4 x, float4 y) {
    union { ushort u[8]; int4 v; } r;
    r.u[0] = f2bf(x.x); r.u[1] = f2bf(x.y); r.u[2] = f2bf(x.z); r.u[3] = f2bf(x.w);
    r.u[4] = f2bf(y.x); r.u[5] = f2bf(y.y); r.u[6] = f2bf(y.z); r.u[7] = f2bf(y.w);
    return r.v;
}

__global__ __launch_bounds__(256, 2) void fused_kernel(
    const float* __restrict__ feat, const float* __restrict__ counts,
    const float* __restrict__ proto, const float* __restrict__ zs,
    const float* __restrict__ temp, const float* __restrict__ W1,
    const float* __restrict__ b1, const float* __restrict__ W2,
    const float* __restrict__ b2,
    float* __restrict__ fpT, unsigned short* __restrict__ ppbT,
    float* __restrict__ dotraw, float* __restrict__ zw,
    float* __restrict__ invf, float* __restrict__ invp,
    float* __restrict__ wbuf, float* __restrict__ out)
{
    cg::grid_group grid = cg::this_grid();
    int bx = blockIdx.x, tid = threadIdx.x;

    __shared__ unsigned short As[2][64 * 72];  // stride 72 halfs: 2-way alias max (free)
    __shared__ unsigned short Bs[2][64 * 72];
    __shared__ float red[16];

    // ================= Phase A =================
    if (bx < 176) {
        // ---- GEMM: 64x64 tiles, BK=64, dbuf LDS, one barrier/iter ----
        const float* A; const float* Bm;
        int lda, ldb, tm, tn, mode;  // 0: fpT (f32 transposed), 1: ppbT (bf16+bias), 2: dotraw
        if (bx < 16) {
            A = feat; lda = 512; Bm = W1; ldb = 1024; mode = 0;
            tm = bx >> 3; tn = bx & 7;
        } else if (bx < 144) {
            int t = bx - 16;
            A = W1 + 512; lda = 1024; Bm = proto; ldb = 512; mode = 1;
            tm = t >> 4; tn = t & 15;
        } else {
            int t = bx - 144;
            A = feat; lda = 512; Bm = proto; ldb = 512; mode = 2;
            tm = t >> 4; tn = t & 15;
        }

        int r = tid >> 2, kq = (tid & 3) * 16;
        int wave = tid >> 6, lane = tid & 63;
        int fr = lane & 15, quad = lane >> 4;

        const float* Ag = A + (size_t)(tm * 64 + r) * lda + kq;
        const float* Bg = Bm + (size_t)(tn * 64 + r) * ldb + kq;

        float4 a0 = *(const float4*)(Ag),      a1 = *(const float4*)(Ag + 4);
        float4 a2 = *(const float4*)(Ag + 8),  a3 = *(const float4*)(Ag + 12);
        float4 g0 = *(const float4*)(Bg),      g1 = *(const float4*)(Bg + 4);
        float4 g2 = *(const float4*)(Bg + 8),  g3 = *(const float4*)(Bg + 12);

        f32x4 acc0 = {0.f, 0.f, 0.f, 0.f};
        f32x4 acc1 = acc0, acc2 = acc0, acc3 = acc0;

        for (int kc = 0; kc < 512; kc += 64) {
            int p = (kc >> 6) & 1;
            *(int4*)&As[p][r * 72 + kq]     = pack_bf16_8(a0, a1);
            *(int4*)&As[p][r * 72 + kq + 8] = pack_bf16_8(a2, a3);
            *(int4*)&Bs[p][r * 72 + kq]     = pack_bf16_8(g0, g1);
            *(int4*)&Bs[p][r * 72 + kq + 8] = pack_bf16_8(g2, g3);
            __syncthreads();
            if (kc + 64 < 512) {
                const float* An = Ag + kc + 64;
                const float* Bn = Bg + kc + 64;
                a0 = *(const float4*)(An);     a1 = *(const float4*)(An + 4);
                a2 = *(const float4*)(An + 8); a3 = *(const float4*)(An + 12);
                g0 = *(const float4*)(Bn);     g1 = *(const float4*)(Bn + 4);
                g2 = *(const float4*)(Bn + 8); g3 = *(const float4*)(Bn + 12);
            }
            #pragma unroll
            for (int s = 0; s < 2; ++s) {
                int ko = s * 32 + quad * 8;
                bhalf8 af  = *(const bhalf8*)&As[p][(wave * 16 + fr) * 72 + ko];
                bhalf8 bf0 = *(const bhalf8*)&Bs[p][(fr) * 72 + ko];
                bhalf8 bf1 = *(const bhalf8*)&Bs[p][(16 + fr) * 72 + ko];
                bhalf8 bf2 = *(const bhalf8*)&Bs[p][(32 + fr) * 72 + ko];
                bhalf8 bf3 = *(const bhalf8*)&Bs[p][(48 + fr) * 72 + ko];
                acc0 = __builtin_amdgcn_mfma_f32_16x16x32_bf16(af, bf0, acc0, 0, 0, 0);
                acc1 = __builtin_amdgcn_mfma_f32_16x16x32_bf16(af, bf1, acc1, 0, 0, 0);
                acc2 = __builtin_amdgcn_mfma_f32_16x16x32_bf16(af, bf2, acc2, 0, 0, 0);
                acc3 = __builtin_amdgcn_mfma_f32_16x16x32_bf16(af, bf3, acc3, 0, 0, 0);
            }
            // single barrier/iter safe: buf[p] rewritten 2 iters later, past next barrier
        }

        // C/D layout: col = lane&15, row = quad*4 + reg  [m89/m91]
        int m0 = tm * 64 + wave * 16 + quad * 4;
        int n0 = tn * 64 + fr;
        f32x4 accs[4] = {acc0, acc1, acc2, acc3};
        if (mode == 0) {
            for (int j = 0; j < 4; ++j)
                for (int rr = 0; rr < 4; ++rr)
                    fpT[(size_t)(n0 + j * 16) * 128 + m0 + rr] = accs[j][rr];
        } else if (mode == 1) {
            float bv4[4];
            for (int rr = 0; rr < 4; ++rr) bv4[rr] = b1[m0 + rr];
            for (int j = 0; j < 4; ++j)
                for (int rr = 0; rr < 4; ++rr)
                    ppbT[(size_t)(m0 + rr) * 1024 + n0 + j * 16] = f2bf(accs[j][rr] + bv4[rr]);
        } else {
            for (int j = 0; j < 4; ++j)
                for (int rr = 0; rr < 4; ++rr)
                    dotraw[(size_t)(m0 + rr) * 1024 + n0 + j * 16] = accs[j][rr];
        }
    } else if (bx < 192) {
        // zipf: 64 i's per block; 4 threads per i scan quarters of j
        float* cn = (float*)&As[0][0];   // reuse LDS
        ((float4*)cn)[tid] = ((const float4*)counts)[tid];
        __syncthreads();
        int il = tid >> 2, q = tid & 3;
        int i = (bx - 176) * 64 + il;
        float ci = cn[i];
        int cnt = 0;
        int j0 = q * 256;
        for (int j = j0; j < j0 + 256; ++j) {
            float cj = cn[j];
            cnt += (cj > ci) ? 1 : 0;
            cnt += (cj == ci && j < i) ? 1 : 0;  // stable tie-break
        }
        cnt += __shfl_xor(cnt, 1);
        cnt += __shfl_xor(cnt, 2);
        if (q == 0) zw[i] = powf((float)(cnt + 1), -zs[0]);
    } else if (bx < 480) {
        // inverse L2 norms: 4 rows/block, 1 wave/row (0..127 feat, 128..1151 proto)
        int nb = bx - 192;
        int w = tid >> 6, lane = tid & 63;
        int row = nb * 4 + w;
        const float* src = (row < 128) ? (feat + (size_t)row * 512)
                                       : (proto + (size_t)(row - 128) * 512);
        const float4* rp = (const float4*)src;
        float4 a = rp[lane * 2], b = rp[lane * 2 + 1];
        float ss = a.x*a.x + a.y*a.y + a.z*a.z + a.w*a.w
                 + b.x*b.x + b.y*b.y + b.z*b.z + b.w*b.w;
        for (int o = 32; o; o >>= 1) ss += __shfl_xor(ss, o);
        if (lane == 0) {
            float inv = 1.0f / fmaxf(sqrtf(ss), 1e-12f);
            if (row < 128) invf[row] = inv; else invp[row - 128] = inv;
        }
    }

    grid.sync();

    // ================= Phase B: w[b,v], b-tile 2, full K =================
    if (bx < 256) {
        int wave = tid >> 6, lane = tid & 63;
        int bg = bx >> 2, vq = bx & 3;
        int b0 = bg * 2;
        int v = vq * 256 + tid;

        // zwsum: each block reduces zw locally (4 KB from L2)
        float4 z4 = ((const float4*)zw)[tid];
        float zsl = z4.x + z4.y + z4.z + z4.w;
        for (int o = 32; o; o >>= 1) zsl += __shfl_xor(zsl, o);
        if (lane == 0) red[wave] = zsl;
        __syncthreads();
        float izw = 1.0f / fmaxf(red[0] + red[1] + red[2] + red[3], 1e-8f);

        float itemp = 1.0f / fmaxf(temp[0], 1e-4f);
        float it0 = invf[b0] * itemp, it1 = invf[b0 + 1] * itemp;
        float b2v = b2[0];
        float zwv = zw[v];
        float ipv = invp[v];
        float dr0 = dotraw[(size_t)b0 * 1024 + v];
        float dr1 = dotraw[(size_t)(b0 + 1) * 1024 + v];

        const unsigned short* pc = ppbT + v;
        const float* fpb = fpT + b0;

        float h0 = 0.f, h1 = 0.f;
        #pragma unroll 8
        for (int k = 0; k < 512; ++k) {
            float p = bf2f(pc[(size_t)k << 10]);
            float2 f = *(const float2*)(fpb + (size_t)k * 128);  // uniform -> s_load
            float w2k = W2[k];                                   // uniform -> s_load
            h0 += fmaxf(f.x + p, 0.f) * w2k;
            h1 += fmaxf(f.y + p, 0.f) * w2k;
        }

        float w0 = (zwv * izw) * (1.0f + dr0 * it0 * ipv) * (1.0f / (1.0f + expf(-(h0 + b2v))));
        float w1 = (zwv * izw) * (1.0f + dr1 * it1 * ipv) * (1.0f / (1.0f + expf(-(h1 + b2v))));
        wbuf[(size_t)b0 * 1024 + v] = w0;
        wbuf[(size_t)(b0 + 1) * 1024 + v] = w1;
    }

    grid.sync();

    // ================= Phase C: softmax per b =================
    if (bx < 128) {
        int wave = tid >> 6, lane = tid & 63;
        int b = bx;
        float4 w4 = *(const float4*)(wbuf + (size_t)b * 1024 + tid * 4);

        float mx = fmaxf(fmaxf(w4.x, w4.y), fmaxf(w4.z, w4.w));
        for (int o = 32; o; o >>= 1) mx = fmaxf(mx, __shfl_xor(mx, o));
        if (lane == 0) red[wave] = mx;
        __syncthreads();
        mx = fmaxf(fmaxf(red[0], red[1]), fmaxf(red[2], red[3]));
        __syncthreads();

        float4 e;
        e.x = expf(w4.x - mx); e.y = expf(w4.y - mx);
        e.z = expf(w4.z - mx); e.w = expf(w4.w - mx);
        float sm = e.x + e.y + e.z + e.w;
        for (int o = 32; o; o >>= 1) sm += __shfl_xor(sm, o);
        if (lane == 0) red[wave] = sm;
        __syncthreads();
        float inv = 1.0f / (red[0] + red[1] + red[2] + red[3]);

        float4 r4;
        r4.x = e.x * inv; r4.y = e.y * inv; r4.z = e.z * inv; r4.w = e.w * inv;
        *(float4*)(out + (size_t)b * 1024 + tid * 4) = r4;
    }
}

// ---------------- launch ----------------
extern "C" void kernel_launch(void* const* d_in, const int* in_sizes, int n_in,
                              void* d_out, int out_size, void* d_ws, size_t ws_size,
                              hipStream_t stream) {
    const float* feat   = (const float*)d_in[0];
    const float* counts = (const float*)d_in[1];
    // d_in[2] total_count: ranks invariant under positive rescale -> unused
    const float* proto  = (const float*)d_in[3];
    const float* zs     = (const float*)d_in[4];
    const float* temp   = (const float*)d_in[5];
    const float* W1     = (const float*)d_in[6];
    const float* b1     = (const float*)d_in[7];
    const float* W2     = (const float*)d_in[8];
    const float* b2     = (const float*)d_in[9];

    char* ws = (char*)d_ws;
    float* zw     = (float*)(ws + 0);              // 1024 f32
    float* invf   = (float*)(ws + 4096);           // 128 f32
    float* invp   = (float*)(ws + 4608);           // 1024 f32
    float* fpT    = (float*)(ws + 8704);           // 512x128 f32 (transposed fp)
    float* dotraw = (float*)(ws + 270848);         // 128x1024 f32
    unsigned short* ppbT = (unsigned short*)(ws + 795136);  // 512x1024 bf16
    float* wbuf   = (float*)(ws + 1843712);        // 128x1024 f32 pre-softmax weights
    float* outp   = (float*)d_out;

    void* args[] = {
        (void*)&feat, (void*)&counts, (void*)&proto, (void*)&zs, (void*)&temp,
        (void*)&W1, (void*)&b1, (void*)&W2, (void*)&b2,
        (void*)&fpT, (void*)&ppbT, (void*)&dotraw, (void*)&zw,
        (void*)&invf, (void*)&invp, (void*)&wbuf, (void*)&outp,
    };
    hipLaunchCooperativeKernel((void*)fused_kernel, dim3(512), dim3(256),
                               args, 0, stream);
}

// Round 5
// 136.983 us; speedup vs baseline: 1.7326x; 1.7326x over previous
//
#include <hip/hip_runtime.h>
#include <hip/hip_bf16.h>

// B=128, V=1024, D=512. TWO kernels (cooperative sync abandoned: R4 showed
// grid.sync costs >100 µs on 8-XCD MI355X):
//  gemm_prep (480 blk x 256 thr):
//    [0,176)  three bf16 MFMA GEMMs, 64x64 tile, BK=256 (2 stages, 3 barriers,
//             all 32 global_load_dwordx4 of a stage issued up-front; stage-1
//             loads overlap stage-0 MFMA):
//               fpT    = (feat @ Wf^T)^T   512x128 f32 (transposed for s_load in head)
//               ppbT   = Wp @ proto^T + b1 512x1024 bf16
//               dotraw = feat @ proto^T    128x1024 f32
//    [176,192) zipf ranks -> zw;  [192,480) row inv-norms
//  head (128 blk x 1024 thr): per (b,v): hs = sum_k relu(fpT[k][b]+ppbT[k][v])*W2[k];
//    w = (zw/sum zw)*(1+sim)*sigmoid(hs+b2); in-block softmax over v -> out

typedef __attribute__((ext_vector_type(8))) short bhalf8;
typedef __attribute__((ext_vector_type(4))) float f32x4;

static __device__ __forceinline__ unsigned short f2bf(float x) {
    union { __hip_bfloat16 h; unsigned short u; } cv;
    cv.h = __float2bfloat16(x);
    return cv.u;
}

static __device__ __forceinline__ float bf2f(unsigned short u) {
    return __uint_as_float(((unsigned int)u) << 16);
}

static __device__ __forceinline__ int4 pack_bf16_8(float4 x, float4 y) {
    union { ushort u[8]; int4 v; } r;
    r.u[0] = f2bf(x.x); r.u[1] = f2bf(x.y); r.u[2] = f2bf(x.z); r.u[3] = f2bf(x.w);
    r.u[4] = f2bf(y.x); r.u[5] = f2bf(y.y); r.u[6] = f2bf(y.z); r.u[7] = f2bf(y.w);
    return r.v;
}

// ---------------- gemm_prep ----------------
__global__ __launch_bounds__(256) void gemm_prep_kernel(
    const float* __restrict__ feat, const float* __restrict__ counts,
    const float* __restrict__ proto, const float* __restrict__ zs,
    const float* __restrict__ W1, const float* __restrict__ b1,
    float* __restrict__ fpT, unsigned short* __restrict__ ppbT,
    float* __restrict__ dotraw,
    float* __restrict__ zw, float* __restrict__ invf, float* __restrict__ invp)
{
    int bx = blockIdx.x, tid = threadIdx.x;

    // LDS: 64 rows x 264 halfs (256 + 8 pad); 2 arrays = 67584 B -> 2 blocks/CU
    __shared__ unsigned short As[64 * 264];
    __shared__ unsigned short Bs[64 * 264];

    if (bx >= 176) {
        if (bx < 192) {
            // zipf: 64 i's per block; 4 threads per i scan quarters of j
            float* cn = (float*)&As[0];
            ((float4*)cn)[tid] = ((const float4*)counts)[tid];
            __syncthreads();
            int il = tid >> 2, q = tid & 3;
            int i = (bx - 176) * 64 + il;
            float ci = cn[i];
            int cnt = 0;
            int j0 = q * 256;
            for (int j = j0; j < j0 + 256; ++j) {
                float cj = cn[j];
                cnt += (cj > ci) ? 1 : 0;
                cnt += (cj == ci && j < i) ? 1 : 0;  // stable tie-break
            }
            cnt += __shfl_xor(cnt, 1);
            cnt += __shfl_xor(cnt, 2);
            if (q == 0) zw[i] = powf((float)(cnt + 1), -zs[0]);
        } else {
            // inverse L2 norms: 4 rows/block, 1 wave/row (0..127 feat, 128..1151 proto)
            int nb = bx - 192;
            int w = tid >> 6, lane = tid & 63;
            int row = nb * 4 + w;
            const float* src = (row < 128) ? (feat + (size_t)row * 512)
                                           : (proto + (size_t)(row - 128) * 512);
            const float4* rp = (const float4*)src;
            float4 a = rp[lane * 2], b = rp[lane * 2 + 1];
            float ss = a.x*a.x + a.y*a.y + a.z*a.z + a.w*a.w
                     + b.x*b.x + b.y*b.y + b.z*b.z + b.w*b.w;
            for (int o = 32; o; o >>= 1) ss += __shfl_xor(ss, o);
            if (lane == 0) {
                float inv = 1.0f / fmaxf(sqrtf(ss), 1e-12f);
                if (row < 128) invf[row] = inv; else invp[row - 128] = inv;
            }
        }
        return;
    }

    // ---- GEMM: 64x64 tile, K=512 in 2 stages of 256 ----
    const float* A; const float* Bm;
    int lda, ldb, tm, tn, mode;  // 0: fpT (f32 transposed), 1: ppbT (bf16+bias), 2: dotraw
    if (bx < 16) {
        A = feat; lda = 512; Bm = W1; ldb = 1024; mode = 0;
        tm = bx >> 3; tn = bx & 7;
    } else if (bx < 144) {
        int t = bx - 16;
        A = W1 + 512; lda = 1024; Bm = proto; ldb = 512; mode = 1;
        tm = t >> 4; tn = t & 15;
    } else {
        int t = bx - 144;
        A = feat; lda = 512; Bm = proto; ldb = 512; mode = 2;
        tm = t >> 4; tn = t & 15;
    }

    int r = tid >> 2, q = tid & 3;           // row 0..63, quarter (64 floats each)
    int wave = tid >> 6, lane = tid & 63;
    int fr = lane & 15, quad = lane >> 4;

    const float* Ag = A + (size_t)(tm * 64 + r) * lda + q * 64;
    const float* Bg = Bm + (size_t)(tn * 64 + r) * ldb + q * 64;
    int lbase = r * 264 + q * 64;            // halfs

    f32x4 acc0 = {0.f, 0.f, 0.f, 0.f};
    f32x4 acc1 = acc0, acc2 = acc0, acc3 = acc0;

    float4 La[16], Lb[16];

    // ---- stage 0 loads (32 dwordx4 in flight) ----
    #pragma unroll
    for (int i = 0; i < 16; ++i) {
        La[i] = *(const float4*)(Ag + i * 4);
        Lb[i] = *(const float4*)(Bg + i * 4);
    }
    #pragma unroll
    for (int j = 0; j < 8; ++j) {
        *(int4*)&As[lbase + j * 8] = pack_bf16_8(La[2*j], La[2*j+1]);
        *(int4*)&Bs[lbase + j * 8] = pack_bf16_8(Lb[2*j], Lb[2*j+1]);
    }
    __syncthreads();

    // ---- stage 1 loads issued BEFORE stage-0 MFMA (hide latency under compute) ----
    #pragma unroll
    for (int i = 0; i < 16; ++i) {
        La[i] = *(const float4*)(Ag + 256 + i * 4);
        Lb[i] = *(const float4*)(Bg + 256 + i * 4);
    }

    // ---- stage 0 MFMA: 8 k-steps ----
    #pragma unroll
    for (int s = 0; s < 8; ++s) {
        int ko = s * 32 + quad * 8;
        bhalf8 af  = *(const bhalf8*)&As[(wave * 16 + fr) * 264 + ko];
        bhalf8 bf0 = *(const bhalf8*)&Bs[(fr) * 264 + ko];
        bhalf8 bf1 = *(const bhalf8*)&Bs[(16 + fr) * 264 + ko];
        bhalf8 bf2 = *(const bhalf8*)&Bs[(32 + fr) * 264 + ko];
        bhalf8 bf3 = *(const bhalf8*)&Bs[(48 + fr) * 264 + ko];
        acc0 = __builtin_amdgcn_mfma_f32_16x16x32_bf16(af, bf0, acc0, 0, 0, 0);
        acc1 = __builtin_amdgcn_mfma_f32_16x16x32_bf16(af, bf1, acc1, 0, 0, 0);
        acc2 = __builtin_amdgcn_mfma_f32_16x16x32_bf16(af, bf2, acc2, 0, 0, 0);
        acc3 = __builtin_amdgcn_mfma_f32_16x16x32_bf16(af, bf3, acc3, 0, 0, 0);
    }
    __syncthreads();   // all waves done reading stage-0 LDS

    #pragma unroll
    for (int j = 0; j < 8; ++j) {
        *(int4*)&As[lbase + j * 8] = pack_bf16_8(La[2*j], La[2*j+1]);
        *(int4*)&Bs[lbase + j * 8] = pack_bf16_8(Lb[2*j], Lb[2*j+1]);
    }
    __syncthreads();

    // ---- stage 1 MFMA ----
    #pragma unroll
    for (int s = 0; s < 8; ++s) {
        int ko = s * 32 + quad * 8;
        bhalf8 af  = *(const bhalf8*)&As[(wave * 16 + fr) * 264 + ko];
        bhalf8 bf0 = *(const bhalf8*)&Bs[(fr) * 264 + ko];
        bhalf8 bf1 = *(const bhalf8*)&Bs[(16 + fr) * 264 + ko];
        bhalf8 bf2 = *(const bhalf8*)&Bs[(32 + fr) * 264 + ko];
        bhalf8 bf3 = *(const bhalf8*)&Bs[(48 + fr) * 264 + ko];
        acc0 = __builtin_amdgcn_mfma_f32_16x16x32_bf16(af, bf0, acc0, 0, 0, 0);
        acc1 = __builtin_amdgcn_mfma_f32_16x16x32_bf16(af, bf1, acc1, 0, 0, 0);
        acc2 = __builtin_amdgcn_mfma_f32_16x16x32_bf16(af, bf2, acc2, 0, 0, 0);
        acc3 = __builtin_amdgcn_mfma_f32_16x16x32_bf16(af, bf3, acc3, 0, 0, 0);
    }

    // C/D layout: col = lane&15, row = quad*4 + reg  [m89/m91]
    int m0 = tm * 64 + wave * 16 + quad * 4;
    int n0 = tn * 64 + fr;
    f32x4 accs[4] = {acc0, acc1, acc2, acc3};
    if (mode == 0) {
        for (int j = 0; j < 4; ++j)
            for (int rr = 0; rr < 4; ++rr)
                fpT[(size_t)(n0 + j * 16) * 128 + m0 + rr] = accs[j][rr];
    } else if (mode == 1) {
        float bv4[4];
        for (int rr = 0; rr < 4; ++rr) bv4[rr] = b1[m0 + rr];
        for (int j = 0; j < 4; ++j)
            for (int rr = 0; rr < 4; ++rr)
                ppbT[(size_t)(m0 + rr) * 1024 + n0 + j * 16] = f2bf(accs[j][rr] + bv4[rr]);
    } else {
        for (int j = 0; j < 4; ++j)
            for (int rr = 0; rr < 4; ++rr)
                dotraw[(size_t)(m0 + rr) * 1024 + n0 + j * 16] = accs[j][rr];
    }
}

// ---------------- head: hs + weights + softmax, one block per b ----------------
__global__ __launch_bounds__(1024) void head_kernel(
    const float* __restrict__ fpT, const unsigned short* __restrict__ ppbT,
    const float* __restrict__ dotraw, const float* __restrict__ zw,
    const float* __restrict__ invf, const float* __restrict__ invp,
    const float* __restrict__ temp, const float* __restrict__ W2,
    const float* __restrict__ b2, float* __restrict__ out)
{
    int b = blockIdx.x, tid = threadIdx.x;
    int wave = tid >> 6, lane = tid & 63;
    int v = tid;
    __shared__ float red[16];

    // zw-sum: 1 element/thread, block reduction
    float zwv = zw[v];
    float zsl = zwv;
    for (int o = 32; o; o >>= 1) zsl += __shfl_xor(zsl, o);
    if (lane == 0) red[wave] = zsl;
    __syncthreads();
    float zsum = 0.f;
    #pragma unroll
    for (int i = 0; i < 16; ++i) zsum += red[i];
    float izw = 1.0f / fmaxf(zsum, 1e-8f);
    __syncthreads();

    // hs: full K loop; ppbT column load coalesced (128 B/wave/k), fpT/W2 -> s_load
    const unsigned short* pc = ppbT + v;
    float h = 0.f;
    #pragma unroll 8
    for (int k = 0; k < 512; ++k) {
        float p = bf2f(pc[(size_t)k << 10]);
        float f = fpT[(size_t)k * 128 + b];   // uniform
        float w2k = W2[k];                    // uniform
        h += fmaxf(f + p, 0.f) * w2k;
    }

    float it  = invf[b] / fmaxf(temp[0], 1e-4f);
    float sim = dotraw[(size_t)b * 1024 + v] * it * invp[v];
    float w = (zwv * izw) * (1.0f + sim) * (1.0f / (1.0f + expf(-(h + b2[0]))));

    // softmax over v (block-wide)
    float mx = w;
    for (int o = 32; o; o >>= 1) mx = fmaxf(mx, __shfl_xor(mx, o));
    if (lane == 0) red[wave] = mx;
    __syncthreads();
    mx = red[0];
    #pragma unroll
    for (int i = 1; i < 16; ++i) mx = fmaxf(mx, red[i]);
    __syncthreads();

    float e = expf(w - mx);
    float sm = e;
    for (int o = 32; o; o >>= 1) sm += __shfl_xor(sm, o);
    if (lane == 0) red[wave] = sm;
    __syncthreads();
    float tot = 0.f;
    #pragma unroll
    for (int i = 0; i < 16; ++i) tot += red[i];

    out[(size_t)b * 1024 + v] = e / tot;
}

// ---------------- launch ----------------
extern "C" void kernel_launch(void* const* d_in, const int* in_sizes, int n_in,
                              void* d_out, int out_size, void* d_ws, size_t ws_size,
                              hipStream_t stream) {
    const float* feat   = (const float*)d_in[0];
    const float* counts = (const float*)d_in[1];
    // d_in[2] total_count: ranks invariant under positive rescale -> unused
    const float* proto  = (const float*)d_in[3];
    const float* zs     = (const float*)d_in[4];
    const float* temp   = (const float*)d_in[5];
    const float* W1     = (const float*)d_in[6];
    const float* b1     = (const float*)d_in[7];
    const float* W2     = (const float*)d_in[8];
    const float* b2     = (const float*)d_in[9];

    char* ws = (char*)d_ws;
    float* zw     = (float*)(ws + 0);              // 1024 f32
    float* invf   = (float*)(ws + 4096);           // 128 f32
    float* invp   = (float*)(ws + 4608);           // 1024 f32
    float* fpT    = (float*)(ws + 8704);           // 512x128 f32 (transposed fp)
    float* dotraw = (float*)(ws + 270848);         // 128x1024 f32
    unsigned short* ppbT = (unsigned short*)(ws + 795136);  // 512x1024 bf16

    gemm_prep_kernel<<<480, 256, 0, stream>>>(feat, counts, proto, zs, W1, b1,
                                              fpT, ppbT, dotraw, zw, invf, invp);
    head_kernel<<<128, 1024, 0, stream>>>(fpT, ppbT, dotraw, zw, invf, invp,
                                          temp, W2, b2, (float*)d_out);
}

// Round 6
// 110.213 us; speedup vs baseline: 2.1534x; 1.2429x over previous
//
#include <hip/hip_runtime.h>
#include <hip/hip_bf16.h>

// B=128, V=1024, D=512. TWO kernels:
//  gemm_prep (480 blk x 256 thr)  [R3-proven structure]:
//    [0,176)  three bf16 MFMA GEMMs, 64x64 tile, BK=64, LDS double-buffered,
//             one barrier/iter, f32 global loads + cvt-to-bf16 in reg:
//               fpT    = (feat @ Wf^T)^T   512x128 f32 (transposed: head s_loads it)
//               ppbT   = Wp @ proto^T + b1 512x1024 bf16
//               dotraw = feat @ proto^T    128x1024 f32
//    [176,192) zipf ranks -> zw;  [192,480) row inv-norms
//  head (128 blk x 1024 thr): tid=(ks 4 x vt 256); thread: 4 consecutive v,
//    k-segment of 128 -> LDS partial; recombine; w=(zw/sum zw)*(1+sim)*sigmoid(hs+b2);
//    block softmax over v -> out.
// Budget model (R1-R5 fit): fill 41us + fixed ~36us harness floor; kernels ~12-16us.

typedef __attribute__((ext_vector_type(8))) short bhalf8;
typedef __attribute__((ext_vector_type(4))) float f32x4;

static __device__ __forceinline__ unsigned short f2bf(float x) {
    union { __hip_bfloat16 h; unsigned short u; } cv;
    cv.h = __float2bfloat16(x);
    return cv.u;
}

static __device__ __forceinline__ float bf2f(unsigned short u) {
    return __uint_as_float(((unsigned int)u) << 16);
}

static __device__ __forceinline__ int4 pack_bf16_8(float4 x, float4 y) {
    union { ushort u[8]; int4 v; } r;
    r.u[0] = f2bf(x.x); r.u[1] = f2bf(x.y); r.u[2] = f2bf(x.z); r.u[3] = f2bf(x.w);
    r.u[4] = f2bf(y.x); r.u[5] = f2bf(y.y); r.u[6] = f2bf(y.z); r.u[7] = f2bf(y.w);
    return r.v;
}

// ---------------- gemm_prep ----------------
__global__ __launch_bounds__(256) void gemm_prep_kernel(
    const float* __restrict__ feat, const float* __restrict__ counts,
    const float* __restrict__ proto, const float* __restrict__ zs,
    const float* __restrict__ W1, const float* __restrict__ b1,
    float* __restrict__ fpT, unsigned short* __restrict__ ppbT,
    float* __restrict__ dotraw,
    float* __restrict__ zw, float* __restrict__ invf, float* __restrict__ invp)
{
    int bx = blockIdx.x, tid = threadIdx.x;

    __shared__ unsigned short As[2][64 * 72];  // stride 72 halfs: 2-way alias max (free)
    __shared__ unsigned short Bs[2][64 * 72];

    if (bx >= 176) {
        if (bx < 192) {
            // zipf: 64 i's per block; 4 threads per i scan quarters of j
            float* cn = (float*)&As[0][0];
            ((float4*)cn)[tid] = ((const float4*)counts)[tid];
            __syncthreads();
            int il = tid >> 2, q = tid & 3;
            int i = (bx - 176) * 64 + il;
            float ci = cn[i];
            int cnt = 0;
            int j0 = q * 256;
            for (int j = j0; j < j0 + 256; ++j) {
                float cj = cn[j];
                cnt += (cj > ci) ? 1 : 0;
                cnt += (cj == ci && j < i) ? 1 : 0;  // stable tie-break
            }
            cnt += __shfl_xor(cnt, 1);
            cnt += __shfl_xor(cnt, 2);
            if (q == 0) zw[i] = powf((float)(cnt + 1), -zs[0]);
        } else {
            // inverse L2 norms: 4 rows/block, 1 wave/row (0..127 feat, 128..1151 proto)
            int nb = bx - 192;
            int w = tid >> 6, lane = tid & 63;
            int row = nb * 4 + w;
            const float* src = (row < 128) ? (feat + (size_t)row * 512)
                                           : (proto + (size_t)(row - 128) * 512);
            const float4* rp = (const float4*)src;
            float4 a = rp[lane * 2], b = rp[lane * 2 + 1];
            float ss = a.x*a.x + a.y*a.y + a.z*a.z + a.w*a.w
                     + b.x*b.x + b.y*b.y + b.z*b.z + b.w*b.w;
            for (int o = 32; o; o >>= 1) ss += __shfl_xor(ss, o);
            if (lane == 0) {
                float inv = 1.0f / fmaxf(sqrtf(ss), 1e-12f);
                if (row < 128) invf[row] = inv; else invp[row - 128] = inv;
            }
        }
        return;
    }

    // ---- GEMM: 64x64 tiles, BK=64, dbuf LDS, one barrier/iter ----
    const float* A; const float* Bm;
    int lda, ldb, tm, tn, mode;  // 0: fpT (f32 transposed), 1: ppbT (bf16+bias), 2: dotraw
    if (bx < 16) {
        A = feat; lda = 512; Bm = W1; ldb = 1024; mode = 0;
        tm = bx >> 3; tn = bx & 7;
    } else if (bx < 144) {
        int t = bx - 16;
        A = W1 + 512; lda = 1024; Bm = proto; ldb = 512; mode = 1;
        tm = t >> 4; tn = t & 15;
    } else {
        int t = bx - 144;
        A = feat; lda = 512; Bm = proto; ldb = 512; mode = 2;
        tm = t >> 4; tn = t & 15;
    }

    int r = tid >> 2, kq = (tid & 3) * 16;
    int wave = tid >> 6, lane = tid & 63;
    int fr = lane & 15, quad = lane >> 4;

    const float* Ag = A + (size_t)(tm * 64 + r) * lda + kq;
    const float* Bg = Bm + (size_t)(tn * 64 + r) * ldb + kq;

    float4 a0 = *(const float4*)(Ag),      a1 = *(const float4*)(Ag + 4);
    float4 a2 = *(const float4*)(Ag + 8),  a3 = *(const float4*)(Ag + 12);
    float4 g0 = *(const float4*)(Bg),      g1 = *(const float4*)(Bg + 4);
    float4 g2 = *(const float4*)(Bg + 8),  g3 = *(const float4*)(Bg + 12);

    f32x4 acc0 = {0.f, 0.f, 0.f, 0.f};
    f32x4 acc1 = acc0, acc2 = acc0, acc3 = acc0;

    for (int kc = 0; kc < 512; kc += 64) {
        int p = (kc >> 6) & 1;
        *(int4*)&As[p][r * 72 + kq]     = pack_bf16_8(a0, a1);
        *(int4*)&As[p][r * 72 + kq + 8] = pack_bf16_8(a2, a3);
        *(int4*)&Bs[p][r * 72 + kq]     = pack_bf16_8(g0, g1);
        *(int4*)&Bs[p][r * 72 + kq + 8] = pack_bf16_8(g2, g3);
        __syncthreads();
        if (kc + 64 < 512) {
            const float* An = Ag + kc + 64;
            const float* Bn = Bg + kc + 64;
            a0 = *(const float4*)(An);     a1 = *(const float4*)(An + 4);
            a2 = *(const float4*)(An + 8); a3 = *(const float4*)(An + 12);
            g0 = *(const float4*)(Bn);     g1 = *(const float4*)(Bn + 4);
            g2 = *(const float4*)(Bn + 8); g3 = *(const float4*)(Bn + 12);
        }
        #pragma unroll
        for (int s = 0; s < 2; ++s) {
            int ko = s * 32 + quad * 8;
            bhalf8 af  = *(const bhalf8*)&As[p][(wave * 16 + fr) * 72 + ko];
            bhalf8 bf0 = *(const bhalf8*)&Bs[p][(fr) * 72 + ko];
            bhalf8 bf1 = *(const bhalf8*)&Bs[p][(16 + fr) * 72 + ko];
            bhalf8 bf2 = *(const bhalf8*)&Bs[p][(32 + fr) * 72 + ko];
            bhalf8 bf3 = *(const bhalf8*)&Bs[p][(48 + fr) * 72 + ko];
            acc0 = __builtin_amdgcn_mfma_f32_16x16x32_bf16(af, bf0, acc0, 0, 0, 0);
            acc1 = __builtin_amdgcn_mfma_f32_16x16x32_bf16(af, bf1, acc1, 0, 0, 0);
            acc2 = __builtin_amdgcn_mfma_f32_16x16x32_bf16(af, bf2, acc2, 0, 0, 0);
            acc3 = __builtin_amdgcn_mfma_f32_16x16x32_bf16(af, bf3, acc3, 0, 0, 0);
        }
        // single barrier/iter safe: buf[p] rewritten 2 iters later, past next barrier
    }

    // C/D layout: col = lane&15, row = quad*4 + reg  [m89/m91]
    int m0 = tm * 64 + wave * 16 + quad * 4;
    int n0 = tn * 64 + fr;
    f32x4 accs[4] = {acc0, acc1, acc2, acc3};
    if (mode == 0) {
        for (int j = 0; j < 4; ++j)
            for (int rr = 0; rr < 4; ++rr)
                fpT[(size_t)(n0 + j * 16) * 128 + m0 + rr] = accs[j][rr];
    } else if (mode == 1) {
        float bv4[4];
        for (int rr = 0; rr < 4; ++rr) bv4[rr] = b1[m0 + rr];
        for (int j = 0; j < 4; ++j)
            for (int rr = 0; rr < 4; ++rr)
                ppbT[(size_t)(m0 + rr) * 1024 + n0 + j * 16] = f2bf(accs[j][rr] + bv4[rr]);
    } else {
        for (int j = 0; j < 4; ++j)
            for (int rr = 0; rr < 4; ++rr)
                dotraw[(size_t)(m0 + rr) * 1024 + n0 + j * 16] = accs[j][rr];
    }
}

// ---------------- head: hs (4-way in-block ksplit) + weights + softmax ----------------
// 128 blocks (b) x 1024 thr: tid = ks*256 + vt; thread: v in [vt*4, vt*4+4),
// k in [ks*128, (ks+1)*128); partials via LDS; then 1 v/thread for combine+softmax.
__global__ __launch_bounds__(1024) void head_kernel(
    const float* __restrict__ fpT, const unsigned short* __restrict__ ppbT,
    const float* __restrict__ dotraw, const float* __restrict__ zw,
    const float* __restrict__ invf, const float* __restrict__ invp,
    const float* __restrict__ temp, const float* __restrict__ W2,
    const float* __restrict__ b2, float* __restrict__ out)
{
    int b = blockIdx.x, tid = threadIdx.x;
    int wave = tid >> 6, lane = tid & 63;
    int vt = tid & 255, ks = tid >> 8;
    int v4 = vt * 4, k0 = ks * 128;

    __shared__ float hpart[4 * 1024];   // 16 KB
    __shared__ float red[16];

    // ---- hs partial: 128 k's x 4 v's ----
    float h0 = 0.f, h1 = 0.f, h2 = 0.f, h3 = 0.f;
    const unsigned short* pc = ppbT + v4;
    #pragma unroll 8
    for (int k = k0; k < k0 + 128; ++k) {
        ushort2 u2 = *(const ushort2*)(pc + ((size_t)k << 10));       // 4 bf16 (8 B)
        unsigned int ua = ((const unsigned int*)&u2)[0];
        unsigned int ub = ((const unsigned int*)&u2)[1];
        float p0 = __uint_as_float(ua << 16);
        float p1 = __uint_as_float(ua & 0xffff0000u);
        float p2 = __uint_as_float(ub << 16);
        float p3 = __uint_as_float(ub & 0xffff0000u);
        float f  = fpT[(size_t)k * 128 + b];   // uniform -> s_load
        float w2 = W2[k];                      // uniform -> s_load
        h0 += fmaxf(f + p0, 0.f) * w2;
        h1 += fmaxf(f + p1, 0.f) * w2;
        h2 += fmaxf(f + p2, 0.f) * w2;
        h3 += fmaxf(f + p3, 0.f) * w2;
    }
    float4 hv = {h0, h1, h2, h3};
    *(float4*)&hpart[ks * 1024 + v4] = hv;

    // zw-sum while partials land (independent of hpart)
    float zwv = zw[tid];
    float zsl = zwv;
    for (int o = 32; o; o >>= 1) zsl += __shfl_xor(zsl, o);
    if (lane == 0) red[wave] = zsl;
    __syncthreads();
    float zsum = 0.f;
    #pragma unroll
    for (int i = 0; i < 16; ++i) zsum += red[i];
    float izw = 1.0f / fmaxf(zsum, 1e-8f);

    // ---- recombine: thread tid handles v = tid ----
    int v = tid;
    float h = hpart[v] + hpart[1024 + v] + hpart[2048 + v] + hpart[3072 + v];

    float it  = invf[b] / fmaxf(temp[0], 1e-4f);
    float sim = dotraw[(size_t)b * 1024 + v] * it * invp[v];
    float w = (zwv * izw) * (1.0f + sim) * (1.0f / (1.0f + expf(-(h + b2[0]))));

    __syncthreads();   // red[] reuse

    // ---- softmax over v ----
    float mx = w;
    for (int o = 32; o; o >>= 1) mx = fmaxf(mx, __shfl_xor(mx, o));
    if (lane == 0) red[wave] = mx;
    __syncthreads();
    mx = red[0];
    #pragma unroll
    for (int i = 1; i < 16; ++i) mx = fmaxf(mx, red[i]);
    __syncthreads();

    float e = expf(w - mx);
    float sm = e;
    for (int o = 32; o; o >>= 1) sm += __shfl_xor(sm, o);
    if (lane == 0) red[wave] = sm;
    __syncthreads();
    float tot = 0.f;
    #pragma unroll
    for (int i = 0; i < 16; ++i) tot += red[i];

    out[(size_t)b * 1024 + v] = e / tot;
}

// ---------------- launch ----------------
extern "C" void kernel_launch(void* const* d_in, const int* in_sizes, int n_in,
                              void* d_out, int out_size, void* d_ws, size_t ws_size,
                              hipStream_t stream) {
    const float* feat   = (const float*)d_in[0];
    const float* counts = (const float*)d_in[1];
    // d_in[2] total_count: ranks invariant under positive rescale -> unused
    const float* proto  = (const float*)d_in[3];
    const float* zs     = (const float*)d_in[4];
    const float* temp   = (const float*)d_in[5];
    const float* W1     = (const float*)d_in[6];
    const float* b1     = (const float*)d_in[7];
    const float* W2     = (const float*)d_in[8];
    const float* b2     = (const float*)d_in[9];

    char* ws = (char*)d_ws;
    float* zw     = (float*)(ws + 0);              // 1024 f32
    float* invf   = (float*)(ws + 4096);           // 128 f32
    float* invp   = (float*)(ws + 4608);           // 1024 f32
    float* fpT    = (float*)(ws + 8704);           // 512x128 f32 (transposed fp)
    float* dotraw = (float*)(ws + 270848);         // 128x1024 f32
    unsigned short* ppbT = (unsigned short*)(ws + 795136);  // 512x1024 bf16

    gemm_prep_kernel<<<480, 256, 0, stream>>>(feat, counts, proto, zs, W1, b1,
                                              fpT, ppbT, dotraw, zw, invf, invp);
    head_kernel<<<128, 1024, 0, stream>>>(fpT, ppbT, dotraw, zw, invf, invp,
                                          temp, W2, b2, (float*)d_out);
}

// Round 7
// 102.650 us; speedup vs baseline: 2.3121x; 1.0737x over previous
//
#include <hip/hip_runtime.h>
#include <hip/hip_bf16.h>

// B=128, V=1024, D=512. THREE kernels (node overhead measured ~free in R2->R3):
//  gemm_prep (480 blk x 256 thr):
//    [0,176)  three bf16 MFMA GEMMs, 64x64 tile, BK=64, LDS dbuf, 1 barrier/iter.
//             EPILOGUE VIA LDS TRANSPOSE -> all d_ws stores are dwordx4 wide
//             (R6 post-mortem: gemm_prep ~40us hiding under the 41us fill; narrow
//              2B/4B scattered d_ws stores suspected transaction-bound):
//               fpT    = (feat @ Wf^T)^T   512x128 f32
//               ppbT   = Wp @ proto^T + b1 512x1024 bf16
//               dotraw = feat @ proto^T    128x1024 f32
//    [176,192) zipf ranks -> zw;  [192,480) row inv-norms
//  head_w (256 blk x 1024 thr): per (b, v-half): hs via int4 ppbT loads (8 v/load),
//    16-way in-block k-split (32-deep), LDS partials; w=(zw/sum zw)*(1+sim)*sigmoid(hs+b2)
//    -> wbuf. Full-chip occupancy (256 blocks).
//  softmax (128 blk x 1024 thr): row softmax wbuf -> out.

typedef __attribute__((ext_vector_type(8))) short bhalf8;
typedef __attribute__((ext_vector_type(4))) float f32x4;

static __device__ __forceinline__ unsigned short f2bf(float x) {
    union { __hip_bfloat16 h; unsigned short u; } cv;
    cv.h = __float2bfloat16(x);
    return cv.u;
}

static __device__ __forceinline__ int4 pack_bf16_8(float4 x, float4 y) {
    union { ushort u[8]; int4 v; } r;
    r.u[0] = f2bf(x.x); r.u[1] = f2bf(x.y); r.u[2] = f2bf(x.z); r.u[3] = f2bf(x.w);
    r.u[4] = f2bf(y.x); r.u[5] = f2bf(y.y); r.u[6] = f2bf(y.z); r.u[7] = f2bf(y.w);
    return r.v;
}

// ---------------- gemm_prep ----------------
__global__ __launch_bounds__(256) void gemm_prep_kernel(
    const float* __restrict__ feat, const float* __restrict__ counts,
    const float* __restrict__ proto, const float* __restrict__ zs,
    const float* __restrict__ W1, const float* __restrict__ b1,
    float* __restrict__ fpT, unsigned short* __restrict__ ppbT,
    float* __restrict__ dotraw,
    float* __restrict__ zw, float* __restrict__ invf, float* __restrict__ invp)
{
    int bx = blockIdx.x, tid = threadIdx.x;

    __shared__ unsigned short As[2][64 * 72];  // 18 KB; epilogue reuses as 64x65 f32
    __shared__ unsigned short Bs[2][64 * 72];

    if (bx >= 176) {
        if (bx < 192) {
            // zipf: 64 i's per block; 4 threads per i scan quarters of j
            float* cn = (float*)&As[0][0];
            ((float4*)cn)[tid] = ((const float4*)counts)[tid];
            __syncthreads();
            int il = tid >> 2, q = tid & 3;
            int i = (bx - 176) * 64 + il;
            float ci = cn[i];
            int cnt = 0;
            int j0 = q * 256;
            #pragma unroll 8
            for (int j = j0; j < j0 + 256; ++j) {
                float cj = cn[j];
                cnt += (cj > ci) ? 1 : 0;
                cnt += (cj == ci && j < i) ? 1 : 0;  // stable tie-break
            }
            cnt += __shfl_xor(cnt, 1);
            cnt += __shfl_xor(cnt, 2);
            if (q == 0) zw[i] = powf((float)(cnt + 1), -zs[0]);
        } else {
            // inverse L2 norms: 4 rows/block, 1 wave/row (0..127 feat, 128..1151 proto)
            int nb = bx - 192;
            int w = tid >> 6, lane = tid & 63;
            int row = nb * 4 + w;
            const float* src = (row < 128) ? (feat + (size_t)row * 512)
                                           : (proto + (size_t)(row - 128) * 512);
            const float4* rp = (const float4*)src;
            float4 a = rp[lane * 2], b = rp[lane * 2 + 1];
            float ss = a.x*a.x + a.y*a.y + a.z*a.z + a.w*a.w
                     + b.x*b.x + b.y*b.y + b.z*b.z + b.w*b.w;
            for (int o = 32; o; o >>= 1) ss += __shfl_xor(ss, o);
            if (lane == 0) {
                float inv = 1.0f / fmaxf(sqrtf(ss), 1e-12f);
                if (row < 128) invf[row] = inv; else invp[row - 128] = inv;
            }
        }
        return;
    }

    // ---- GEMM: 64x64 tiles, BK=64, dbuf LDS, one barrier/iter ----
    const float* A; const float* Bm;
    int lda, ldb, tm, tn, mode;  // 0: fpT (f32 transposed), 1: ppbT (bf16+bias), 2: dotraw
    if (bx < 16) {
        A = feat; lda = 512; Bm = W1; ldb = 1024; mode = 0;
        tm = bx >> 3; tn = bx & 7;
    } else if (bx < 144) {
        int t = bx - 16;
        A = W1 + 512; lda = 1024; Bm = proto; ldb = 512; mode = 1;
        tm = t >> 4; tn = t & 15;
    } else {
        int t = bx - 144;
        A = feat; lda = 512; Bm = proto; ldb = 512; mode = 2;
        tm = t >> 4; tn = t & 15;
    }

    int r = tid >> 2, kq = (tid & 3) * 16;
    int wave = tid >> 6, lane = tid & 63;
    int fr = lane & 15, quad = lane >> 4;

    const float* Ag = A + (size_t)(tm * 64 + r) * lda + kq;
    const float* Bg = Bm + (size_t)(tn * 64 + r) * ldb + kq;

    float4 a0 = *(const float4*)(Ag),      a1 = *(const float4*)(Ag + 4);
    float4 a2 = *(const float4*)(Ag + 8),  a3 = *(const float4*)(Ag + 12);
    float4 g0 = *(const float4*)(Bg),      g1 = *(const float4*)(Bg + 4);
    float4 g2 = *(const float4*)(Bg + 8),  g3 = *(const float4*)(Bg + 12);

    f32x4 acc0 = {0.f, 0.f, 0.f, 0.f};
    f32x4 acc1 = acc0, acc2 = acc0, acc3 = acc0;

    for (int kc = 0; kc < 512; kc += 64) {
        int p = (kc >> 6) & 1;
        *(int4*)&As[p][r * 72 + kq]     = pack_bf16_8(a0, a1);
        *(int4*)&As[p][r * 72 + kq + 8] = pack_bf16_8(a2, a3);
        *(int4*)&Bs[p][r * 72 + kq]     = pack_bf16_8(g0, g1);
        *(int4*)&Bs[p][r * 72 + kq + 8] = pack_bf16_8(g2, g3);
        __syncthreads();
        if (kc + 64 < 512) {
            const float* An = Ag + kc + 64;
            const float* Bn = Bg + kc + 64;
            a0 = *(const float4*)(An);     a1 = *(const float4*)(An + 4);
            a2 = *(const float4*)(An + 8); a3 = *(const float4*)(An + 12);
            g0 = *(const float4*)(Bn);     g1 = *(const float4*)(Bn + 4);
            g2 = *(const float4*)(Bn + 8); g3 = *(const float4*)(Bn + 12);
        }
        #pragma unroll
        for (int s = 0; s < 2; ++s) {
            int ko = s * 32 + quad * 8;
            bhalf8 af  = *(const bhalf8*)&As[p][(wave * 16 + fr) * 72 + ko];
            bhalf8 bf0 = *(const bhalf8*)&Bs[p][(fr) * 72 + ko];
            bhalf8 bf1 = *(const bhalf8*)&Bs[p][(16 + fr) * 72 + ko];
            bhalf8 bf2 = *(const bhalf8*)&Bs[p][(32 + fr) * 72 + ko];
            bhalf8 bf3 = *(const bhalf8*)&Bs[p][(48 + fr) * 72 + ko];
            acc0 = __builtin_amdgcn_mfma_f32_16x16x32_bf16(af, bf0, acc0, 0, 0, 0);
            acc1 = __builtin_amdgcn_mfma_f32_16x16x32_bf16(af, bf1, acc1, 0, 0, 0);
            acc2 = __builtin_amdgcn_mfma_f32_16x16x32_bf16(af, bf2, acc2, 0, 0, 0);
            acc3 = __builtin_amdgcn_mfma_f32_16x16x32_bf16(af, bf3, acc3, 0, 0, 0);
        }
        // single barrier/iter safe: buf[p] rewritten 2 iters later, past next barrier
    }

    // ---- epilogue: C-tile -> LDS (64x65 f32) -> WIDE dwordx4 global stores ----
    __syncthreads();                       // all waves done with LDS main-loop reads
    float* Ct = (float*)&As[0][0];         // 64*65*4 = 16640 B <= 18432 B (As)
    {
        // C/D layout: col = lane&15, row = quad*4 + reg  [m89/m91]
        int rl = wave * 16 + quad * 4;
        f32x4 accs[4] = {acc0, acc1, acc2, acc3};
        #pragma unroll
        for (int j = 0; j < 4; ++j)
            #pragma unroll
            for (int rr = 0; rr < 4; ++rr)
                Ct[(rl + rr) * 65 + fr + j * 16] = accs[j][rr];
    }
    __syncthreads();

    int tr = tid >> 2, tq = tid & 3;       // tr 0..63 (tile row = m), tq: 16-col chunk
    if (mode == 0) {
        // fpT[k=n][b=m]: thread reads LDS column (m = tq*16+i) at row... we need
        // k-major: output row = n = tr, cols = m-range tq*16..+16
        float o[16];
        #pragma unroll
        for (int i = 0; i < 16; ++i) o[i] = Ct[(tq * 16 + i) * 65 + tr];
        float* dst = fpT + (size_t)(tn * 64 + tr) * 128 + tm * 64 + tq * 16;
        #pragma unroll
        for (int c = 0; c < 4; ++c) {
            float4 v = {o[c*4], o[c*4+1], o[c*4+2], o[c*4+3]};
            *(float4*)(dst + c * 4) = v;
        }
    } else if (mode == 1) {
        // ppbT[k=m][v=n] bf16 + bias(m): row tr, cols tq*16..+16 -> 2 int4 stores
        float bv = b1[tm * 64 + tr];
        float o[16];
        #pragma unroll
        for (int i = 0; i < 16; ++i) o[i] = Ct[tr * 65 + tq * 16 + i] + bv;
        unsigned short* dst = ppbT + (size_t)(tm * 64 + tr) * 1024 + tn * 64 + tq * 16;
        float4 x0 = {o[0], o[1], o[2], o[3]},   y0 = {o[4], o[5], o[6], o[7]};
        float4 x1 = {o[8], o[9], o[10], o[11]}, y1 = {o[12], o[13], o[14], o[15]};
        *(int4*)(dst)     = pack_bf16_8(x0, y0);
        *(int4*)(dst + 8) = pack_bf16_8(x1, y1);
    } else {
        // dotraw[m][n] f32: row tr, cols tq*16..+16 -> 4 float4 stores
        float* dst = dotraw + (size_t)(tm * 64 + tr) * 1024 + tn * 64 + tq * 16;
        #pragma unroll
        for (int c = 0; c < 4; ++c) {
            float4 v = {Ct[tr * 65 + tq * 16 + c*4],     Ct[tr * 65 + tq * 16 + c*4 + 1],
                        Ct[tr * 65 + tq * 16 + c*4 + 2], Ct[tr * 65 + tq * 16 + c*4 + 3]};
            *(float4*)(dst + c * 4) = v;
        }
    }
}

// ---------------- head_w: hs + weights -> wbuf. 256 blocks (b x v-half) x 1024 ----------------
// tid = ks*64 + vt: ks in [0,16) k-segment of 32; vt in [0,64) -> 8 v's via one int4/k.
__global__ __launch_bounds__(1024) void head_w_kernel(
    const float* __restrict__ fpT, const unsigned short* __restrict__ ppbT,
    const float* __restrict__ dotraw, const float* __restrict__ zw,
    const float* __restrict__ invf, const float* __restrict__ invp,
    const float* __restrict__ temp, const float* __restrict__ W2,
    const float* __restrict__ b2, float* __restrict__ wbuf)
{
    int bx = blockIdx.x, tid = threadIdx.x;
    int b = bx >> 1, bh = bx & 1;
    int wave = tid >> 6, lane = tid & 63;
    int vt = tid & 63, ks = tid >> 6;         // ks 0..15
    int vl8 = vt * 8;                          // local v (0..511), 8 per thread
    int v8 = bh * 512 + vl8;                   // global v
    int k0 = ks * 32;

    __shared__ float hpart[16 * 512];          // 32 KB
    __shared__ float red[16];

    // zw-sum first (all 1024 threads cover all 1024 v)
    float zwt = zw[tid];
    float zsl = zwt;
    for (int o = 32; o; o >>= 1) zsl += __shfl_xor(zsl, o);
    if (lane == 0) red[wave] = zsl;
    __syncthreads();
    float zsum = 0.f;
    #pragma unroll
    for (int i = 0; i < 16; ++i) zsum += red[i];
    float izw = 1.0f / fmaxf(zsum, 1e-8f);

    // hs partial: 32 k's x 8 v's; int4 = 8 bf16 per load, unroll 8 -> deep ILP
    float2 h01 = {0.f, 0.f}, h23 = h01, h45 = h01, h67 = h01;
    const unsigned short* pc = ppbT + v8;
    #pragma unroll 8
    for (int k = k0; k < k0 + 32; ++k) {
        int4 pv = *(const int4*)(pc + ((size_t)k << 10));
        unsigned int u0 = (unsigned int)pv.x, u1 = (unsigned int)pv.y;
        unsigned int u2 = (unsigned int)pv.z, u3 = (unsigned int)pv.w;
        float f  = fpT[(size_t)k * 128 + b];   // uniform -> s_load
        float w2 = W2[k];                      // uniform -> s_load
        float2 p01 = {__uint_as_float(u0 << 16), __uint_as_float(u0 & 0xffff0000u)};
        float2 p23 = {__uint_as_float(u1 << 16), __uint_as_float(u1 & 0xffff0000u)};
        float2 p45 = {__uint_as_float(u2 << 16), __uint_as_float(u2 & 0xffff0000u)};
        float2 p67 = {__uint_as_float(u3 << 16), __uint_as_float(u3 & 0xffff0000u)};
        h01.x += fmaxf(f + p01.x, 0.f) * w2;  h01.y += fmaxf(f + p01.y, 0.f) * w2;
        h23.x += fmaxf(f + p23.x, 0.f) * w2;  h23.y += fmaxf(f + p23.y, 0.f) * w2;
        h45.x += fmaxf(f + p45.x, 0.f) * w2;  h45.y += fmaxf(f + p45.y, 0.f) * w2;
        h67.x += fmaxf(f + p67.x, 0.f) * w2;  h67.y += fmaxf(f + p67.y, 0.f) * w2;
    }
    float4 ha = {h01.x, h01.y, h23.x, h23.y};
    float4 hb = {h45.x, h45.y, h67.x, h67.y};
    *(float4*)&hpart[ks * 512 + vl8]     = ha;
    *(float4*)&hpart[ks * 512 + vl8 + 4] = hb;
    __syncthreads();

    // recombine + weights: threads [0,512) handle one local v each
    if (tid < 512) {
        int vl = tid, v = bh * 512 + vl;
        float h = 0.f;
        #pragma unroll
        for (int s = 0; s < 16; ++s) h += hpart[s * 512 + vl];

        float it  = invf[b] / fmaxf(temp[0], 1e-4f);
        float sim = dotraw[(size_t)b * 1024 + v] * it * invp[v];
        float w = (zw[v] * izw) * (1.0f + sim) * (1.0f / (1.0f + expf(-(h + b2[0]))));
        wbuf[(size_t)b * 1024 + v] = w;
    }
}

// ---------------- softmax: one block per b ----------------
__global__ __launch_bounds__(1024) void softmax_kernel(
    const float* __restrict__ wbuf, float* __restrict__ out)
{
    int b = blockIdx.x, tid = threadIdx.x;
    int wave = tid >> 6, lane = tid & 63;
    __shared__ float red[16];

    float w = wbuf[(size_t)b * 1024 + tid];

    float mx = w;
    for (int o = 32; o; o >>= 1) mx = fmaxf(mx, __shfl_xor(mx, o));
    if (lane == 0) red[wave] = mx;
    __syncthreads();
    mx = red[0];
    #pragma unroll
    for (int i = 1; i < 16; ++i) mx = fmaxf(mx, red[i]);
    __syncthreads();

    float e = expf(w - mx);
    float sm = e;
    for (int o = 32; o; o >>= 1) sm += __shfl_xor(sm, o);
    if (lane == 0) red[wave] = sm;
    __syncthreads();
    float tot = 0.f;
    #pragma unroll
    for (int i = 0; i < 16; ++i) tot += red[i];

    out[(size_t)b * 1024 + tid] = e / tot;
}

// ---------------- launch ----------------
extern "C" void kernel_launch(void* const* d_in, const int* in_sizes, int n_in,
                              void* d_out, int out_size, void* d_ws, size_t ws_size,
                              hipStream_t stream) {
    const float* feat   = (const float*)d_in[0];
    const float* counts = (const float*)d_in[1];
    // d_in[2] total_count: ranks invariant under positive rescale -> unused
    const float* proto  = (const float*)d_in[3];
    const float* zs     = (const float*)d_in[4];
    const float* temp   = (const float*)d_in[5];
    const float* W1     = (const float*)d_in[6];
    const float* b1     = (const float*)d_in[7];
    const float* W2     = (const float*)d_in[8];
    const float* b2     = (const float*)d_in[9];

    char* ws = (char*)d_ws;
    float* zw     = (float*)(ws + 0);              // 1024 f32
    float* invf   = (float*)(ws + 4096);           // 128 f32
    float* invp   = (float*)(ws + 4608);           // 1024 f32
    float* fpT    = (float*)(ws + 8704);           // 512x128 f32 (transposed fp)
    float* dotraw = (float*)(ws + 270848);         // 128x1024 f32
    unsigned short* ppbT = (unsigned short*)(ws + 795136);  // 512x1024 bf16
    float* wbuf   = (float*)(ws + 1843712);        // 128x1024 f32

    gemm_prep_kernel<<<480, 256, 0, stream>>>(feat, counts, proto, zs, W1, b1,
                                              fpT, ppbT, dotraw, zw, invf, invp);
    head_w_kernel<<<256, 1024, 0, stream>>>(fpT, ppbT, dotraw, zw, invf, invp,
                                            temp, W2, b2, wbuf);
    softmax_kernel<<<128, 1024, 0, stream>>>(wbuf, (float*)d_out);
}